// Round 1
// baseline (500.623 us; speedup 1.0000x reference)
//
#include <hip/hip_runtime.h>
#include <math.h>

#define KK 128
#define EE 4096
#define MM 512
#define MAXNZ 32

// ws layout (in floats):
//   [0, 128)               u_cur
//   [128, 128+2048)        partials (K rows x 16 e-tiles)
//   [2176, 2176+4096)      cnt[e]      (int)
//   [6272, 6272+4096*32)   idx[e][32]  (int)
//   [137344 ...)           per-e consts: P01, a2, sc, invd, bz  (5 x 4096 floats)
#define OFF_PART 128
#define OFF_CNT  2176
#define OFF_IDX  6272
#define OFF_PE   137344

__global__ __launch_bounds__(256) void k_setup(
    const float* __restrict__ U, const float* __restrict__ beiTa_2,
    const float* __restrict__ guess_slip, const float* __restrict__ A_emb,
    const float* __restrict__ gamma_c, const float* __restrict__ score,
    const float* __restrict__ q_kn, const float* __restrict__ d,
    const int* __restrict__ stu_id, float* __restrict__ ws)
{
    int e = blockIdx.x * 256 + threadIdx.x;  // grid exactly covers E
    int* cnt = (int*)(ws + OFF_CNT);
    int* idx = (int*)(ws + OFF_IDX);
    float* P01  = ws + OFF_PE;
    float* a2   = P01 + EE;
    float* scv  = a2 + EE;
    float* invd = scv + EE;
    float* bz   = invd + EE;

    // build sparse support of q_kn row e (binary matrix, ~5 nnz/row)
    const float4* qrow = (const float4*)(q_kn + (size_t)e * KK);
    int c = 0;
    for (int j4 = 0; j4 < KK / 4; j4++) {
        float4 q = qrow[j4];
        int j = j4 * 4;
        if (q.x > 0.5f) { if (c < MAXNZ) idx[e * MAXNZ + c] = j;     c++; }
        if (q.y > 0.5f) { if (c < MAXNZ) idx[e * MAXNZ + c] = j + 1; c++; }
        if (q.z > 0.5f) { if (c < MAXNZ) idx[e * MAXNZ + c] = j + 2; c++; }
        if (q.w > 0.5f) { if (c < MAXNZ) idx[e * MAXNZ + c] = j + 3; c++; }
    }
    cnt[e] = (c < MAXNZ) ? c : MAXNZ;

    // iteration-invariant per-e constants
    float id_ = 1.0f / d[e];
    invd[e] = id_;
    float scr = score[e];
    scv[e] = scr;
    P01[e] = A_emb[3 * e] * (1.0f - guess_slip[2 * e]) +
             A_emb[3 * e + 1] * (1.0f - guess_slip[2 * e + 1]);
    a2[e] = A_emb[3 * e + 2];
    float zc = 1.0f / (1.0f + __expf(gamma_c[e] * id_ * (scr - 0.5f))) - 0.5f;
    bz[e] = beiTa_2[e] * zc;

    // u0 = U_embeding[stu_id]
    if (blockIdx.x == 0 && threadIdx.x < KK) {
        ws[threadIdx.x] = U[(size_t)stu_id[0] * KK + threadIdx.x];
    }
}

// One (k, e-tile-of-256) per block. Sparse gather of B over support of e.
__global__ __launch_bounds__(256) void k_iter(
    const float* __restrict__ B, const float* __restrict__ W,
    const float* __restrict__ beiTa_1, const float* __restrict__ ukc,
    float* __restrict__ ws)
{
    __shared__ float lu[KK];
    __shared__ float ldv[KK];
    __shared__ float red[256];
    int tid = threadIdx.x;
    int k = blockIdx.y;
    int e = blockIdx.x * 256 + tid;

    if (tid < KK) {
        float uv = ws[tid];
        lu[tid] = uv;
        float t = uv - 0.5f;
        ldv[tid] = (fabsf(t) > 0.05f) ? t : 0.0f;
    }
    __syncthreads();

    const int* cnt = (const int*)(ws + OFF_CNT);
    const int* ip  = (const int*)(ws + OFF_IDX) + e * MAXNZ;
    const float* P01  = ws + OFF_PE;
    const float* a2   = P01 + EE;
    const float* scv  = a2 + EE;
    const float* invd = scv + EE;
    const float* bz   = invd + EE;

    int c = cnt[e];
    const float* Brow = B + ((size_t)k * EE + (size_t)e) * KK;
    float su = 0.0f, gs = 0.0f;
    for (int i = 0; i < c; i++) {
        int j = ip[i];
        su += lu[j];
        float dvj = ldv[j];
        if (j != k && dvj != 0.0f) gs += Brow[j] * dvj;  // diag term cancels exactly
    }
    float t0 = scv[e] - su * invd[e];
    float yc = __expf(-t0 * t0);
    float Ic  = 1.0f / (1.0f + __expf(P01[e] + a2[e] * yc));
    float Gkc = 1.0f / (1.0f + __expf(gs)) - 1.0f;
    size_t o = (size_t)k * EE + (size_t)e;
    float WKv = Ic * (beiTa_1[o] * Gkc + bz[e]);
    float contrib = ukc[o] * W[o] * WKv;

    red[tid] = contrib;
    __syncthreads();
    for (int s2 = 128; s2 > 0; s2 >>= 1) {
        if (tid < s2) red[tid] += red[tid + s2];
        __syncthreads();
    }
    if (tid == 0) ws[OFF_PART + k * 16 + blockIdx.x] = red[0];
}

// state update for iterations 0 and 1 (one block, 128 threads)
__global__ __launch_bounds__(128) void k_update(float* __restrict__ ws,
                                                float* __restrict__ out, int iter)
{
    __shared__ float red[KK];
    int k = threadIdx.x;
    float s = 0.0f;
    for (int t = 0; t < 16; t++) s += ws[OFF_PART + k * 16 + t];
    float un = 1.0f / (1.0f + __expf(s));
    float uo = ws[k];
    float dd = un - uo;
    red[k] = dd * dd;
    __syncthreads();
    for (int s2 = 64; s2 > 0; s2 >>= 1) {
        if (k < s2) red[k] += red[k + s2];
        __syncthreads();
    }
    if (k == 0) out[768 + iter] = sqrtf(red[0]);
    ws[k] = un;
    if (iter == 1) out[128 + k] = un;  // state_2nd_last
}

// final: last update + diff + predict (one block, 512 threads)
__global__ __launch_bounds__(512) void k_final(
    float* __restrict__ ws, float* __restrict__ out,
    const int* __restrict__ ex_id, const float* __restrict__ alpha,
    const float* __restrict__ gamma_e)
{
    __shared__ float un_s[KK];
    __shared__ float red[KK];
    int tid = threadIdx.x;
    if (tid < KK) {
        float s = 0.0f;
        for (int t = 0; t < 16; t++) s += ws[OFF_PART + tid * 16 + t];
        float un = 1.0f / (1.0f + __expf(s));
        float uo = ws[tid];
        float dd = un - uo;
        red[tid] = dd * dd;
        un_s[tid] = un;
        out[tid] = un;  // state_last
    }
    __syncthreads();
    for (int s2 = 64; s2 > 0; s2 >>= 1) {
        if (tid < s2) red[tid] += red[tid + s2];
        __syncthreads();
    }
    if (tid == 0) out[770] = sqrtf(red[0]);

    // predict for m = tid (512 threads == M)
    const int* cnt = (const int*)(ws + OFF_CNT);
    const int* idx = (const int*)(ws + OFF_IDX);
    const float* invd = ws + OFF_PE + 3 * EE;
    int e = ex_id[tid];
    int c = cnt[e];
    const int* ip = idx + e * MAXNZ;
    float su = 0.0f;
    for (int i = 0; i < c; i++) su += un_s[ip[i]];
    float Ukse = su * invd[e] - 0.5f;
    float p = 1.0f / (1.0f + __expf(alpha[e] * Ukse + gamma_e[e]));
    out[256 + tid] = p;
}

extern "C" void kernel_launch(void* const* d_in, const int* in_sizes, int n_in,
                              void* d_out, int out_size, void* d_ws, size_t ws_size,
                              hipStream_t stream) {
    const float* U          = (const float*)d_in[0];
    const float* W          = (const float*)d_in[1];
    const float* beiTa_1    = (const float*)d_in[2];
    const float* beiTa_2    = (const float*)d_in[3];
    const float* B          = (const float*)d_in[4];
    const float* guess_slip = (const float*)d_in[5];
    const float* A_emb      = (const float*)d_in[6];
    const float* gamma_c    = (const float*)d_in[7];
    const float* gamma_e    = (const float*)d_in[8];
    const float* alpha      = (const float*)d_in[9];
    const float* score      = (const float*)d_in[10];
    const float* ukc        = (const float*)d_in[11];
    const float* q_kn       = (const float*)d_in[12];
    const float* d          = (const float*)d_in[13];
    const int*   stu_id     = (const int*)d_in[14];
    const int*   ex_id      = (const int*)d_in[16];
    float* out = (float*)d_out;
    float* ws  = (float*)d_ws;

    k_setup<<<16, 256, 0, stream>>>(U, beiTa_2, guess_slip, A_emb, gamma_c,
                                    score, q_kn, d, stu_id, ws);
    for (int iter = 0; iter < 3; iter++) {
        k_iter<<<dim3(16, 128), 256, 0, stream>>>(B, W, beiTa_1, ukc, ws);
        if (iter < 2) {
            k_update<<<1, 128, 0, stream>>>(ws, out, iter);
        } else {
            k_final<<<1, 512, 0, stream>>>(ws, out, ex_id, alpha, gamma_e);
        }
    }
}